// Round 18
// baseline (56.636 us; speedup 1.0000x reference)
//
#include <hip/hip_runtime.h>
#include <math.h>

// ---- DCT constants (fp32) ----
#define A0c 0.35355339059327373f
#define C1c 0.4903926402016152f
#define C2c 0.46193976625564337f
#define C3c 0.41573480615127262f
#define C5c 0.27778511650980114f
#define C6c 0.19134171618254492f
#define C7c 0.09754516100806417f

#define IMG_W 512
#define IMG_HW (512 * 512)

typedef float f8v __attribute__((ext_vector_type(8)));

// base JPEG tables, ORIGINAL orientation (QUALITY=50 -> scaled == base)
__device__ const float QLUM[64] = {
    16,11,10,16,24,40,51,61,  12,12,14,19,26,58,60,55,
    14,13,16,24,40,57,69,56,  14,17,22,29,51,87,80,62,
    18,22,37,56,68,109,103,77, 24,35,55,64,81,104,113,92,
    49,64,78,87,103,121,120,101, 72,92,95,98,112,100,103,99};
__device__ const float QCHR[64] = {
    17,18,24,47,99,99,99,99,  18,21,26,66,99,99,99,99,
    24,26,56,99,99,99,99,99,  47,66,99,99,99,99,99,99,
    99,99,99,99,99,99,99,99,  99,99,99,99,99,99,99,99,
    99,99,99,99,99,99,99,99,  99,99,99,99,99,99,99,99};

// In-place 8-point DCT-II (scalar, R6-proven)
__device__ __forceinline__ void fdct8(float v[8]) {
    float s0 = v[0] + v[7], s1 = v[1] + v[6], s2 = v[2] + v[5], s3 = v[3] + v[4];
    float d0 = v[0] - v[7], d1 = v[1] - v[6], d2 = v[2] - v[5], d3 = v[3] - v[4];
    float e0 = s0 + s3, e1 = s1 + s2, f0 = s0 - s3, f1 = s1 - s2;
    v[0] = A0c * (e0 + e1);
    v[4] = A0c * (e0 - e1);
    v[2] = C2c * f0 + C6c * f1;
    v[6] = C6c * f0 - C2c * f1;
    v[1] = C1c * d0 + C3c * d1 + C5c * d2 + C7c * d3;
    v[3] = C3c * d0 - C7c * d1 - C1c * d2 - C5c * d3;
    v[5] = C5c * d0 - C1c * d1 + C7c * d2 + C3c * d3;
    v[7] = C7c * d0 - C5c * d1 + C3c * d2 - C1c * d3;
}

// In-place 8-point inverse (scalar, R6-proven)
__device__ __forceinline__ void idct8(float v[8]) {
    float g0 = v[0], g1 = v[1], g2 = v[2], g3 = v[3];
    float g4 = v[4], g5 = v[5], g6 = v[6], g7 = v[7];
    float ep = A0c * (g0 + g4), em = A0c * (g0 - g4);
    float t26a = C2c * g2 + C6c * g6;
    float t26b = C6c * g2 - C2c * g6;
    float e0 = ep + t26a, e1 = em + t26b, e2 = em - t26b, e3 = ep - t26a;
    float o0 = C1c * g1 + C3c * g3 + C5c * g5 + C7c * g7;
    float o1 = C3c * g1 - C7c * g3 - C1c * g5 - C5c * g7;
    float o2 = C5c * g1 - C1c * g3 + C7c * g5 + C3c * g7;
    float o3 = C7c * g1 - C5c * g3 + C3c * g5 - C1c * g7;
    v[0] = e0 + o0; v[7] = e0 - o0;
    v[1] = e1 + o1; v[6] = e1 - o1;
    v[2] = e2 + o2; v[5] = e2 - o2;
    v[3] = e3 + o3; v[4] = e3 - o3;
}

// soft quantize-dequantize: deq = x + qh*tanh(15t), qh = 0.5q, t = d - round(d)
#define K_EXP2 43.2808512266689f
__device__ __forceinline__ float softq(float x, float qh, float rq) {
    float d = x * rq;
    float rn = rintf(d);                   // nearest-even, matches jnp.round
    float t = d - rn;
    float e2 = __builtin_amdgcn_exp2f(K_EXP2 * t);
    float th = (e2 - 1.0f) * __builtin_amdgcn_rcpf(e2 + 1.0f);
    return x + qh * th;
}

// compiler-only fence: forbids reordering LDS ops across it (zero instructions).
#define LDS_FENCE() asm volatile("" ::: "memory")

// R14 body verbatim (38.8us best); ONLY change: nontemporal output stores.
// Theory: the 96MB/iter store stream evicts the input from L3 between timed
// iterations (FETCH showed ~50% input miss). NT stores deprioritize cache
// allocation -> input stays L3-resident -> FETCH collapses, HBM traffic
// ~148MB -> ~100MB.
__global__ __launch_bounds__(256) void jpeg_kernel(const float* __restrict__ x,
                                                   float* __restrict__ out) {
    __shared__ float xpose[4][576];   // per-wave transpose scratch (9216 B)
    __shared__ float qtab[4][64];     // 0:qhL 1:rqL 2:qhC 3:rqC, [v*8+u]

    const int tid = threadIdx.x;
    const int wid = tid >> 6;
    const int lane = tid & 63;

    const int gw = blockIdx.x * 4 + wid;     // 0..16383
    const int bimg = gw >> 9;                // image
    const int rem = gw & 511;
    const int gh = rem >> 3;                 // 8-row strip index
    const int tx = rem & 7;                  // 64-col tile index

    const int blk = lane & 7;                // 8x8 block within tile
    const int row = lane >> 3;               // row within strip / freq v

    const size_t off = (size_t)bimg * 3 * IMG_HW +
                       (size_t)(gh * 8 + row) * IMG_W + tx * 64 + blk * 8;
    const float* base = x + off;

    // issue global loads first; qtab init overlaps their latency
    const f8v Rv = *(const f8v*)(base);
    const f8v Gv = *(const f8v*)(base + IMG_HW);
    const f8v Bv = *(const f8v*)(base + 2 * IMG_HW);

    // qtab init: benign duplicate writes per wave; in-order DS per wave.
    {
        int u = lane & 7, v = lane >> 3;     // qtab[.][v*8+u] = f(Q[u][v])
        float ql = QLUM[u * 8 + v];
        float qc = QCHR[u * 8 + v];
        qtab[0][lane] = 0.5f * ql;
        qtab[1][lane] = __builtin_amdgcn_rcpf(ql);
        qtab[2][lane] = 0.5f * qc;
        qtab[3][lane] = __builtin_amdgcn_rcpf(qc);
    }
    LDS_FENCE();

    float* xp = xpose[wid];
    const int wbase = blk * 9 + row;         // write: xp[j*72 + wbase]
    const int rbase = row * 72 + blk * 9;    // read:  xp[rbase + k]
    const int qrow = row * 8;

    // ---- forward color (all channels, in regs) ----
    float g0[8], g1[8], g2[8];
#pragma unroll
    for (int k = 0; k < 8; ++k) {
        float R = Rv[k], G = Gv[k], B = Bv[k];
        g0[k] = 0.299f * R + 0.587f * G + 0.114f * B - 0.5f;
        g1[k] = -0.168736f * R - 0.331264f * G + 0.5f * B;
        g2[k] = 0.5f * R - 0.418688f * G - 0.081312f * B;
    }

    // ================= channel 0 (luma) =================
    fdct8(g0);
#pragma unroll
    for (int j = 0; j < 8; ++j) xp[j * 72 + wbase] = g0[j];
    LDS_FENCE();
#pragma unroll
    for (int k = 0; k < 8; ++k) g0[k] = xp[rbase + k];
    LDS_FENCE();
    fdct8(g0);
    {
        float4 qa = *(const float4*)&qtab[0][qrow];
        float4 qb = *(const float4*)&qtab[0][qrow + 4];
        float4 ra = *(const float4*)&qtab[1][qrow];
        float4 rb = *(const float4*)&qtab[1][qrow + 4];
        g0[0] = softq(g0[0], qa.x, ra.x); g0[1] = softq(g0[1], qa.y, ra.y);
        g0[2] = softq(g0[2], qa.z, ra.z); g0[3] = softq(g0[3], qa.w, ra.w);
        g0[4] = softq(g0[4], qb.x, rb.x); g0[5] = softq(g0[5], qb.y, rb.y);
        g0[6] = softq(g0[6], qb.z, rb.z); g0[7] = softq(g0[7], qb.w, rb.w);
    }
    idct8(g0);
    LDS_FENCE();
#pragma unroll
    for (int j = 0; j < 8; ++j) xp[j * 72 + wbase] = g0[j];
    LDS_FENCE();
#pragma unroll
    for (int k = 0; k < 8; ++k) g0[k] = xp[rbase + k];
    LDS_FENCE();
    idct8(g0);

    // ================= channel 1 (Cb) =================
    fdct8(g1);
#pragma unroll
    for (int j = 0; j < 8; ++j) xp[j * 72 + wbase] = g1[j];
    LDS_FENCE();
#pragma unroll
    for (int k = 0; k < 8; ++k) g1[k] = xp[rbase + k];
    LDS_FENCE();
    fdct8(g1);
    {
        float4 qa = *(const float4*)&qtab[2][qrow];
        float4 qb = *(const float4*)&qtab[2][qrow + 4];
        float4 ra = *(const float4*)&qtab[3][qrow];
        float4 rb = *(const float4*)&qtab[3][qrow + 4];
        g1[0] = softq(g1[0], qa.x, ra.x); g1[1] = softq(g1[1], qa.y, ra.y);
        g1[2] = softq(g1[2], qa.z, ra.z); g1[3] = softq(g1[3], qa.w, ra.w);
        g1[4] = softq(g1[4], qb.x, rb.x); g1[5] = softq(g1[5], qb.y, rb.y);
        g1[6] = softq(g1[6], qb.z, rb.z); g1[7] = softq(g1[7], qb.w, rb.w);
    }
    idct8(g1);
    LDS_FENCE();
#pragma unroll
    for (int j = 0; j < 8; ++j) xp[j * 72 + wbase] = g1[j];
    LDS_FENCE();
#pragma unroll
    for (int k = 0; k < 8; ++k) g1[k] = xp[rbase + k];
    LDS_FENCE();
    idct8(g1);

    // ================= channel 2 (Cr) =================
    fdct8(g2);
#pragma unroll
    for (int j = 0; j < 8; ++j) xp[j * 72 + wbase] = g2[j];
    LDS_FENCE();
#pragma unroll
    for (int k = 0; k < 8; ++k) g2[k] = xp[rbase + k];
    LDS_FENCE();
    fdct8(g2);
    {
        float4 qa = *(const float4*)&qtab[2][qrow];
        float4 qb = *(const float4*)&qtab[2][qrow + 4];
        float4 ra = *(const float4*)&qtab[3][qrow];
        float4 rb = *(const float4*)&qtab[3][qrow + 4];
        g2[0] = softq(g2[0], qa.x, ra.x); g2[1] = softq(g2[1], qa.y, ra.y);
        g2[2] = softq(g2[2], qa.z, ra.z); g2[3] = softq(g2[3], qa.w, ra.w);
        g2[4] = softq(g2[4], qb.x, rb.x); g2[5] = softq(g2[5], qb.y, rb.y);
        g2[6] = softq(g2[6], qb.z, rb.z); g2[7] = softq(g2[7], qb.w, rb.w);
    }
    idct8(g2);
    LDS_FENCE();
#pragma unroll
    for (int j = 0; j < 8; ++j) xp[j * 72 + wbase] = g2[j];
    LDS_FENCE();
#pragma unroll
    for (int k = 0; k < 8; ++k) g2[k] = xp[rbase + k];
    LDS_FENCE();
    idct8(g2);

    // ---- inverse color + coalesced NONTEMPORAL stores ----
    f8v Ro, Go, Bo;
#pragma unroll
    for (int k = 0; k < 8; ++k) {
        float Y  = g0[k] + 0.5f;
        float Cb = g1[k];
        float Cr = g2[k];
        float R = Y + 1.402f * Cr;
        float G = Y - 0.344136f * Cb - 0.714136f * Cr;
        float B = Y + 1.772f * Cb;
        Ro[k] = fminf(fmaxf(R, 0.0f), 1.0f);
        Go[k] = fminf(fmaxf(G, 0.0f), 1.0f);
        Bo[k] = fminf(fmaxf(B, 0.0f), 1.0f);
    }
    float* obase = out + off;
    __builtin_nontemporal_store(Ro, (f8v*)(obase));
    __builtin_nontemporal_store(Go, (f8v*)(obase + IMG_HW));
    __builtin_nontemporal_store(Bo, (f8v*)(obase + 2 * IMG_HW));
}

extern "C" void kernel_launch(void* const* d_in, const int* in_sizes, int n_in,
                              void* d_out, int out_size, void* d_ws, size_t ws_size,
                              hipStream_t stream) {
    const float* x = (const float*)d_in[0];
    float* out = (float*)d_out;
    const int B = in_sizes[0] / (3 * IMG_HW);   // 32
    const int n_wg = B * 128;                   // one tile per wave, 4 waves/WG
    hipLaunchKernelGGL(jpeg_kernel, dim3(n_wg), dim3(256), 0, stream, x, out);
}

// Round 19
// 39.750 us; speedup vs baseline: 1.4248x; 1.4248x over previous
//
#include <hip/hip_runtime.h>
#include <math.h>

// ---- DCT constants (fp32) ----
#define A0c 0.35355339059327373f
#define C1c 0.4903926402016152f
#define C2c 0.46193976625564337f
#define C3c 0.41573480615127262f
#define C5c 0.27778511650980114f
#define C6c 0.19134171618254492f
#define C7c 0.09754516100806417f

#define IMG_W 512
#define IMG_HW (512 * 512)

typedef float f8v __attribute__((ext_vector_type(8)));

// base JPEG tables, ORIGINAL orientation (QUALITY=50 -> scaled == base)
__device__ const float QLUM[64] = {
    16,11,10,16,24,40,51,61,  12,12,14,19,26,58,60,55,
    14,13,16,24,40,57,69,56,  14,17,22,29,51,87,80,62,
    18,22,37,56,68,109,103,77, 24,35,55,64,81,104,113,92,
    49,64,78,87,103,121,120,101, 72,92,95,98,112,100,103,99};
__device__ const float QCHR[64] = {
    17,18,24,47,99,99,99,99,  18,21,26,66,99,99,99,99,
    24,26,56,99,99,99,99,99,  47,66,99,99,99,99,99,99,
    99,99,99,99,99,99,99,99,  99,99,99,99,99,99,99,99,
    99,99,99,99,99,99,99,99,  99,99,99,99,99,99,99,99};

// In-place 8-point DCT-II (scalar, R6-proven)
__device__ __forceinline__ void fdct8(float v[8]) {
    float s0 = v[0] + v[7], s1 = v[1] + v[6], s2 = v[2] + v[5], s3 = v[3] + v[4];
    float d0 = v[0] - v[7], d1 = v[1] - v[6], d2 = v[2] - v[5], d3 = v[3] - v[4];
    float e0 = s0 + s3, e1 = s1 + s2, f0 = s0 - s3, f1 = s1 - s2;
    v[0] = A0c * (e0 + e1);
    v[4] = A0c * (e0 - e1);
    v[2] = C2c * f0 + C6c * f1;
    v[6] = C6c * f0 - C2c * f1;
    v[1] = C1c * d0 + C3c * d1 + C5c * d2 + C7c * d3;
    v[3] = C3c * d0 - C7c * d1 - C1c * d2 - C5c * d3;
    v[5] = C5c * d0 - C1c * d1 + C7c * d2 + C3c * d3;
    v[7] = C7c * d0 - C5c * d1 + C3c * d2 - C1c * d3;
}

// In-place 8-point inverse (scalar, R6-proven)
__device__ __forceinline__ void idct8(float v[8]) {
    float g0 = v[0], g1 = v[1], g2 = v[2], g3 = v[3];
    float g4 = v[4], g5 = v[5], g6 = v[6], g7 = v[7];
    float ep = A0c * (g0 + g4), em = A0c * (g0 - g4);
    float t26a = C2c * g2 + C6c * g6;
    float t26b = C6c * g2 - C2c * g6;
    float e0 = ep + t26a, e1 = em + t26b, e2 = em - t26b, e3 = ep - t26a;
    float o0 = C1c * g1 + C3c * g3 + C5c * g5 + C7c * g7;
    float o1 = C3c * g1 - C7c * g3 - C1c * g5 - C5c * g7;
    float o2 = C5c * g1 - C1c * g3 + C7c * g5 + C3c * g7;
    float o3 = C7c * g1 - C5c * g3 + C3c * g5 - C1c * g7;
    v[0] = e0 + o0; v[7] = e0 - o0;
    v[1] = e1 + o1; v[6] = e1 - o1;
    v[2] = e2 + o2; v[5] = e2 - o2;
    v[3] = e3 + o3; v[4] = e3 - o3;
}

// soft quantize-dequantize: deq = x + qh*tanh(15t), qh = 0.5q, t = d - round(d)
#define K_EXP2 43.2808512266689f
__device__ __forceinline__ float softq(float x, float qh, float rq) {
    float d = x * rq;
    float rn = rintf(d);                   // nearest-even, matches jnp.round
    float t = d - rn;
    float e2 = __builtin_amdgcn_exp2f(K_EXP2 * t);
    float th = (e2 - 1.0f) * __builtin_amdgcn_rcpf(e2 + 1.0f);
    return x + qh * th;
}

// compiler-only fence: forbids reordering LDS ops across it (zero instructions).
#define LDS_FENCE() asm volatile("" ::: "memory")

// R14 structure; single delta: skew-12 transpose layout so read bursts are
// 16B-aligned -> 2x ds_read_b128 instead of 8x ds_read_b32 per transpose
// (DS cyc/tile ~700 -> ~570). Bank math: write xp[j*96+blk*12+row] hits
// (12blk+row)%32 = 16 distinct banks per 16-lane phase; read b128 at
// row*96+blk*12 spans banks 12blk..12blk+3, 2-way aliased across the two
// rows in a phase = free (m136). R13 failed this WITHOUT fences (compiler
// reordered the bursts); fences at every boundary now pin it.
__global__ __launch_bounds__(256) void jpeg_kernel(const float* __restrict__ x,
                                                   float* __restrict__ out) {
    __shared__ float xpose[4][768];   // per-wave transpose scratch (12288 B)
    __shared__ float qtab[4][64];     // 0:qhL 1:rqL 2:qhC 3:rqC, [v*8+u]

    const int tid = threadIdx.x;
    const int wid = tid >> 6;
    const int lane = tid & 63;

    const int gw = blockIdx.x * 4 + wid;     // 0..16383
    const int bimg = gw >> 9;                // image
    const int rem = gw & 511;
    const int gh = rem >> 3;                 // 8-row strip index
    const int tx = rem & 7;                  // 64-col tile index

    const int blk = lane & 7;                // 8x8 block within tile
    const int row = lane >> 3;               // row within strip / freq v

    const size_t off = (size_t)bimg * 3 * IMG_HW +
                       (size_t)(gh * 8 + row) * IMG_W + tx * 64 + blk * 8;
    const float* base = x + off;

    // issue global loads first; qtab init overlaps their latency
    const f8v Rv = *(const f8v*)(base);
    const f8v Gv = *(const f8v*)(base + IMG_HW);
    const f8v Bv = *(const f8v*)(base + 2 * IMG_HW);

    // qtab init: benign duplicate writes per wave; in-order DS per wave.
    {
        int u = lane & 7, v = lane >> 3;     // qtab[.][v*8+u] = f(Q[u][v])
        float ql = QLUM[u * 8 + v];
        float qc = QCHR[u * 8 + v];
        qtab[0][lane] = 0.5f * ql;
        qtab[1][lane] = __builtin_amdgcn_rcpf(ql);
        qtab[2][lane] = 0.5f * qc;
        qtab[3][lane] = __builtin_amdgcn_rcpf(qc);
    }
    LDS_FENCE();

    float* xp = xpose[wid];
    const int wbase = blk * 12 + row;        // write: xp[j*96 + wbase]
    const int rbase = row * 96 + blk * 12;   // read:  xp[rbase..rbase+7], 16B-aligned
    const int qrow = row * 8;

    // ---- forward color (all channels, in regs) ----
    float g0[8], g1[8], g2[8];
#pragma unroll
    for (int k = 0; k < 8; ++k) {
        float R = Rv[k], G = Gv[k], B = Bv[k];
        g0[k] = 0.299f * R + 0.587f * G + 0.114f * B - 0.5f;
        g1[k] = -0.168736f * R - 0.331264f * G + 0.5f * B;
        g2[k] = 0.5f * R - 0.418688f * G - 0.081312f * B;
    }

    // ================= channel 0 (luma) =================
    fdct8(g0);
#pragma unroll
    for (int j = 0; j < 8; ++j) xp[j * 96 + wbase] = g0[j];
    LDS_FENCE();
    {
        float4 lo = *(const float4*)&xp[rbase];
        float4 hi = *(const float4*)&xp[rbase + 4];
        g0[0] = lo.x; g0[1] = lo.y; g0[2] = lo.z; g0[3] = lo.w;
        g0[4] = hi.x; g0[5] = hi.y; g0[6] = hi.z; g0[7] = hi.w;
    }
    LDS_FENCE();
    fdct8(g0);
    {
        float4 qa = *(const float4*)&qtab[0][qrow];
        float4 qb = *(const float4*)&qtab[0][qrow + 4];
        float4 ra = *(const float4*)&qtab[1][qrow];
        float4 rb = *(const float4*)&qtab[1][qrow + 4];
        g0[0] = softq(g0[0], qa.x, ra.x); g0[1] = softq(g0[1], qa.y, ra.y);
        g0[2] = softq(g0[2], qa.z, ra.z); g0[3] = softq(g0[3], qa.w, ra.w);
        g0[4] = softq(g0[4], qb.x, rb.x); g0[5] = softq(g0[5], qb.y, rb.y);
        g0[6] = softq(g0[6], qb.z, rb.z); g0[7] = softq(g0[7], qb.w, rb.w);
    }
    idct8(g0);
    LDS_FENCE();
#pragma unroll
    for (int j = 0; j < 8; ++j) xp[j * 96 + wbase] = g0[j];
    LDS_FENCE();
    {
        float4 lo = *(const float4*)&xp[rbase];
        float4 hi = *(const float4*)&xp[rbase + 4];
        g0[0] = lo.x; g0[1] = lo.y; g0[2] = lo.z; g0[3] = lo.w;
        g0[4] = hi.x; g0[5] = hi.y; g0[6] = hi.z; g0[7] = hi.w;
    }
    LDS_FENCE();
    idct8(g0);

    // ================= channel 1 (Cb) =================
    fdct8(g1);
#pragma unroll
    for (int j = 0; j < 8; ++j) xp[j * 96 + wbase] = g1[j];
    LDS_FENCE();
    {
        float4 lo = *(const float4*)&xp[rbase];
        float4 hi = *(const float4*)&xp[rbase + 4];
        g1[0] = lo.x; g1[1] = lo.y; g1[2] = lo.z; g1[3] = lo.w;
        g1[4] = hi.x; g1[5] = hi.y; g1[6] = hi.z; g1[7] = hi.w;
    }
    LDS_FENCE();
    fdct8(g1);
    {
        float4 qa = *(const float4*)&qtab[2][qrow];
        float4 qb = *(const float4*)&qtab[2][qrow + 4];
        float4 ra = *(const float4*)&qtab[3][qrow];
        float4 rb = *(const float4*)&qtab[3][qrow + 4];
        g1[0] = softq(g1[0], qa.x, ra.x); g1[1] = softq(g1[1], qa.y, ra.y);
        g1[2] = softq(g1[2], qa.z, ra.z); g1[3] = softq(g1[3], qa.w, ra.w);
        g1[4] = softq(g1[4], qb.x, rb.x); g1[5] = softq(g1[5], qb.y, rb.y);
        g1[6] = softq(g1[6], qb.z, rb.z); g1[7] = softq(g1[7], qb.w, rb.w);
    }
    idct8(g1);
    LDS_FENCE();
#pragma unroll
    for (int j = 0; j < 8; ++j) xp[j * 96 + wbase] = g1[j];
    LDS_FENCE();
    {
        float4 lo = *(const float4*)&xp[rbase];
        float4 hi = *(const float4*)&xp[rbase + 4];
        g1[0] = lo.x; g1[1] = lo.y; g1[2] = lo.z; g1[3] = lo.w;
        g1[4] = hi.x; g1[5] = hi.y; g1[6] = hi.z; g1[7] = hi.w;
    }
    LDS_FENCE();
    idct8(g1);

    // ================= channel 2 (Cr) =================
    fdct8(g2);
#pragma unroll
    for (int j = 0; j < 8; ++j) xp[j * 96 + wbase] = g2[j];
    LDS_FENCE();
    {
        float4 lo = *(const float4*)&xp[rbase];
        float4 hi = *(const float4*)&xp[rbase + 4];
        g2[0] = lo.x; g2[1] = lo.y; g2[2] = lo.z; g2[3] = lo.w;
        g2[4] = hi.x; g2[5] = hi.y; g2[6] = hi.z; g2[7] = hi.w;
    }
    LDS_FENCE();
    fdct8(g2);
    {
        float4 qa = *(const float4*)&qtab[2][qrow];
        float4 qb = *(const float4*)&qtab[2][qrow + 4];
        float4 ra = *(const float4*)&qtab[3][qrow];
        float4 rb = *(const float4*)&qtab[3][qrow + 4];
        g2[0] = softq(g2[0], qa.x, ra.x); g2[1] = softq(g2[1], qa.y, ra.y);
        g2[2] = softq(g2[2], qa.z, ra.z); g2[3] = softq(g2[3], qa.w, ra.w);
        g2[4] = softq(g2[4], qb.x, rb.x); g2[5] = softq(g2[5], qb.y, rb.y);
        g2[6] = softq(g2[6], qb.z, rb.z); g2[7] = softq(g2[7], qb.w, rb.w);
    }
    idct8(g2);
    LDS_FENCE();
#pragma unroll
    for (int j = 0; j < 8; ++j) xp[j * 96 + wbase] = g2[j];
    LDS_FENCE();
    {
        float4 lo = *(const float4*)&xp[rbase];
        float4 hi = *(const float4*)&xp[rbase + 4];
        g2[0] = lo.x; g2[1] = lo.y; g2[2] = lo.z; g2[3] = lo.w;
        g2[4] = hi.x; g2[5] = hi.y; g2[6] = hi.z; g2[7] = hi.w;
    }
    LDS_FENCE();
    idct8(g2);

    // ---- inverse color + coalesced stores ----
    f8v Ro, Go, Bo;
#pragma unroll
    for (int k = 0; k < 8; ++k) {
        float Y  = g0[k] + 0.5f;
        float Cb = g1[k];
        float Cr = g2[k];
        float R = Y + 1.402f * Cr;
        float G = Y - 0.344136f * Cb - 0.714136f * Cr;
        float B = Y + 1.772f * Cb;
        Ro[k] = fminf(fmaxf(R, 0.0f), 1.0f);
        Go[k] = fminf(fmaxf(G, 0.0f), 1.0f);
        Bo[k] = fminf(fmaxf(B, 0.0f), 1.0f);
    }
    float* obase = out + off;
    *(f8v*)(obase) = Ro;
    *(f8v*)(obase + IMG_HW) = Go;
    *(f8v*)(obase + 2 * IMG_HW) = Bo;
}

extern "C" void kernel_launch(void* const* d_in, const int* in_sizes, int n_in,
                              void* d_out, int out_size, void* d_ws, size_t ws_size,
                              hipStream_t stream) {
    const float* x = (const float*)d_in[0];
    float* out = (float*)d_out;
    const int B = in_sizes[0] / (3 * IMG_HW);   // 32
    const int n_wg = B * 128;                   // one tile per wave, 4 waves/WG
    hipLaunchKernelGGL(jpeg_kernel, dim3(n_wg), dim3(256), 0, stream, x, out);
}